// Round 4
// baseline (883.438 us; speedup 1.0000x reference)
//
#include <hip/hip_runtime.h>
#include <hip/hip_bf16.h>

// Problem constants (FEDformerEncoder): BS=32 CNT=128 W=2048 P=1024 E=8 K=25 L=2
#define BSZ 32
#define CNTS 128
#define WD 2048
#define PD 1024
#define ED 8
#define KSZ 25
#define LN 2
#define MROWS (BSZ*CNTS)   // 4096

typedef __hip_bfloat16 bf16;
typedef __attribute__((ext_vector_type(8))) short short8;  // 8 bf16 = 4 VGPRs
typedef __attribute__((ext_vector_type(4))) float f32x4;

#define PI_F 3.14159265358979323846f

// ---------------------------------------------------------------------------
// f32 -> (hi, lo) bf16 pair conversion. n multiple of 4.
// ---------------------------------------------------------------------------
__global__ __launch_bounds__(256) void cvt_pair(
    const float* __restrict__ src, bf16* __restrict__ dh, bf16* __restrict__ dl, int n)
{
    const int i = (blockIdx.x * 256 + threadIdx.x) * 4;
    if (i >= n) return;
    const float4 v = *(const float4*)(src + i);
    float a[4] = {v.x, v.y, v.z, v.w};
    bf16 hh[4], ll[4];
    #pragma unroll
    for (int t = 0; t < 4; ++t) {
        hh[t] = __float2bfloat16(a[t]);
        ll[t] = __float2bfloat16(a[t] - __bfloat162float(hh[t]));
    }
    *(ulonglong1*)(dh + i) = *(const ulonglong1*)hh;
    *(ulonglong1*)(dl + i) = *(const ulonglong1*)ll;
}

// ---------------------------------------------------------------------------
// MoE conv: mean over E of conv1d(x, w_e)+b_e == conv1d(x, mean_e w_e)+mean_e b_e
// f32 in, hi/lo bf16-pair out (A operand for the split-MFMA GEMM).
// ---------------------------------------------------------------------------
__global__ __launch_bounds__(256) void conv_moe(
    const float* __restrict__ xin,   // [4096, 2048] f32
    const float* __restrict__ cw,    // [E, K] layer slice
    const float* __restrict__ cb,    // [E]
    bf16* __restrict__ xh, bf16* __restrict__ xl)  // [4096, 2048] bf16 each
{
    __shared__ float srow[WD];
    __shared__ float swb[KSZ];
    __shared__ float sbb;
    const int tid = threadIdx.x;
    const size_t row = blockIdx.x;
    if (tid < KSZ) {
        float s = 0.f;
        for (int e = 0; e < ED; ++e) s += cw[e*KSZ + tid];
        swb[tid] = s * (1.f/ED);
    }
    if (tid == 32) {
        float s = 0.f;
        for (int e = 0; e < ED; ++e) s += cb[e];
        sbb = s * (1.f/ED);
    }
    const float* xr = xin + row*WD;
    for (int i = tid; i < WD; i += 256) srow[i] = xr[i];
    __syncthreads();
    const float bb = sbb;
    for (int t0 = 0; t0 < WD; t0 += 256) {
        const int t = t0 + tid;
        float acc = bb;
        #pragma unroll
        for (int k = 0; k < KSZ; ++k) {
            const int idx = t + k - (KSZ/2);
            const float xv = (idx >= 0 && idx < WD) ? srow[idx] : 0.f;
            acc = fmaf(xv, swb[k], acc);
        }
        const bf16 h = __float2bfloat16(acc);
        const bf16 l = __float2bfloat16(acc - __bfloat162float(h));
        xh[row*WD + t] = h;
        xl[row*WD + t] = l;
    }
}

// ---------------------------------------------------------------------------
// Split-A+B bf16 MFMA GEMM (3-term: AhBh + AlBh + AhBl ~= fp32 exact), B^T:
//   out[m,n] = sum_k A[m,k]*B[n,k] + bias[n]   (f32 out)
// 128x128 tile, BK=32, 256 threads = 4 waves (2x2 of 64x64), m97 staging.
// grid.z selects among 3 (B, bias, out) sets (QKV batching).
// ---------------------------------------------------------------------------
__global__ __launch_bounds__(256, 2) void gemm_split3(
    const bf16* __restrict__ Ah, const bf16* __restrict__ Al,   // [M, K]
    const bf16* __restrict__ Bh0, const bf16* __restrict__ Bl0,
    const bf16* __restrict__ Bh1, const bf16* __restrict__ Bl1,
    const bf16* __restrict__ Bh2, const bf16* __restrict__ Bl2, // [N, K]
    const float* __restrict__ c0, const float* __restrict__ c1, const float* __restrict__ c2, // [N]
    float* o0, float* o1, float* o2,
    const int K, const int N)
{
    const int z = blockIdx.z;
    const bf16*  Bh   = (z == 0) ? Bh0 : (z == 1) ? Bh1 : Bh2;
    const bf16*  Bl   = (z == 0) ? Bl0 : (z == 1) ? Bl1 : Bl2;
    const float* bias = (z == 0) ? c0 : (z == 1) ? c1 : c2;
    float* const out  = (z == 0) ? o0 : (z == 1) ? o1 : o2;

    __shared__ bf16 sAh[128*32];
    __shared__ bf16 sAl[128*32];
    __shared__ bf16 sBh[128*32];
    __shared__ bf16 sBl[128*32];
    const int tid  = threadIdx.x;
    const int m0   = blockIdx.x * 128;
    const int n0   = blockIdx.y * 128;
    const int lane = tid & 63;
    const int wave = tid >> 6;
    const int wm   = (wave >> 1) * 64;
    const int wn   = (wave & 1) * 64;
    const int quad = lane >> 4;
    const int r16  = lane & 15;

    f32x4 acc[4][4] = {};

    // staging chunks: chunk c covers s*[c*8 .. c*8+7] == row (c>>2), cols (c&3)*8..+7
    const int ci0 = tid, ci1 = 256 + tid;
    const int ra0 = ci0 >> 2, ca0 = (ci0 & 3) * 8;
    const int ra1 = ci1 >> 2, ca1 = (ci1 & 3) * 8;

    for (int kb = 0; kb < K; kb += 32) {
        const size_t a0 = (size_t)(m0 + ra0) * K + kb + ca0;
        const size_t a1 = (size_t)(m0 + ra1) * K + kb + ca1;
        const size_t b0 = (size_t)(n0 + ra0) * K + kb + ca0;
        const size_t b1 = (size_t)(n0 + ra1) * K + kb + ca1;
        __builtin_amdgcn_global_load_lds((const __attribute__((address_space(1))) unsigned int*)(Ah + a0),
            (__attribute__((address_space(3))) unsigned int*)&sAh[ci0*8], 16, 0, 0);
        __builtin_amdgcn_global_load_lds((const __attribute__((address_space(1))) unsigned int*)(Ah + a1),
            (__attribute__((address_space(3))) unsigned int*)&sAh[ci1*8], 16, 0, 0);
        __builtin_amdgcn_global_load_lds((const __attribute__((address_space(1))) unsigned int*)(Al + a0),
            (__attribute__((address_space(3))) unsigned int*)&sAl[ci0*8], 16, 0, 0);
        __builtin_amdgcn_global_load_lds((const __attribute__((address_space(1))) unsigned int*)(Al + a1),
            (__attribute__((address_space(3))) unsigned int*)&sAl[ci1*8], 16, 0, 0);
        __builtin_amdgcn_global_load_lds((const __attribute__((address_space(1))) unsigned int*)(Bh + b0),
            (__attribute__((address_space(3))) unsigned int*)&sBh[ci0*8], 16, 0, 0);
        __builtin_amdgcn_global_load_lds((const __attribute__((address_space(1))) unsigned int*)(Bh + b1),
            (__attribute__((address_space(3))) unsigned int*)&sBh[ci1*8], 16, 0, 0);
        __builtin_amdgcn_global_load_lds((const __attribute__((address_space(1))) unsigned int*)(Bl + b0),
            (__attribute__((address_space(3))) unsigned int*)&sBl[ci0*8], 16, 0, 0);
        __builtin_amdgcn_global_load_lds((const __attribute__((address_space(1))) unsigned int*)(Bl + b1),
            (__attribute__((address_space(3))) unsigned int*)&sBl[ci1*8], 16, 0, 0);
        __syncthreads();

        short8 afh[4], afl[4];
        #pragma unroll
        for (int i = 0; i < 4; ++i) {
            afh[i] = *(const short8*)&sAh[(wm + i*16 + r16)*32 + quad*8];
            afl[i] = *(const short8*)&sAl[(wm + i*16 + r16)*32 + quad*8];
        }
        #pragma unroll
        for (int j = 0; j < 4; ++j) {
            const short8 bh = *(const short8*)&sBh[(wn + j*16 + r16)*32 + quad*8];
            const short8 bl = *(const short8*)&sBl[(wn + j*16 + r16)*32 + quad*8];
            #pragma unroll
            for (int i = 0; i < 4; ++i) {
                acc[i][j] = __builtin_amdgcn_mfma_f32_16x16x32_bf16(afh[i], bh, acc[i][j], 0, 0, 0);
                acc[i][j] = __builtin_amdgcn_mfma_f32_16x16x32_bf16(afl[i], bh, acc[i][j], 0, 0, 0);
                acc[i][j] = __builtin_amdgcn_mfma_f32_16x16x32_bf16(afh[i], bl, acc[i][j], 0, 0, 0);
            }
        }
        __syncthreads();
    }

    // epilogue: C/D mapping (16x16x32): col = lane&15, row = quad*4 + r
    #pragma unroll
    for (int j = 0; j < 4; ++j) {
        const int col = n0 + wn + j*16 + r16;
        const float bv = bias[col];
        #pragma unroll
        for (int i = 0; i < 4; ++i) {
            #pragma unroll
            for (int r = 0; r < 4; ++r) {
                const int rowg = m0 + wm + i*16 + quad*4 + r;
                out[(size_t)rowg*N + col] = acc[i][j][r] + bv;
            }
        }
    }
}

// ---------------------------------------------------------------------------
// In-LDS radix-2 DIT FFT, 1024 points, 256 threads (2 butterflies/thread/stage)
// ---------------------------------------------------------------------------
__device__ inline void fft1024(float* re, float* im, const int tid)
{
    for (int i = tid; i < 1024; i += 256) {
        const int j = __brev((unsigned)i) >> 22;
        if (i < j) {
            float t = re[i]; re[i] = re[j]; re[j] = t;
            t = im[i]; im[i] = im[j]; im[j] = t;
        }
    }
    __syncthreads();
    for (int s = 1; s <= 10; ++s) {
        const int half = 1 << (s - 1);
        for (int t = tid; t < 512; t += 256) {
            const int pos = t & (half - 1);
            const int grp = t >> (s - 1);
            const int i = (grp << s) + pos;
            const int j = i + half;
            float wr, wi;
            __sincosf(-PI_F * pos / half, &wi, &wr);
            const float xr = re[j], xi = im[j];
            const float tr = wr*xr - wi*xi;
            const float ti = wr*xi + wi*xr;
            const float ur = re[i], ui = im[i];
            re[j] = ur - tr; im[j] = ui - ti;
            re[i] = ur + tr; im[i] = ui + ti;
        }
        __syncthreads();
    }
}

// ---------------------------------------------------------------------------
// FFT-domain attention: wv = ifft( fft(k) * conj(fft(q)) / 32 * fft(v) ).real
// Hermitian spectrum (real inputs) -> .real exact.
// Re(ifft(S)) = Re(FFT(conj(S)))/N. Output as hi/lo bf16 pair (next GEMM's A).
// ---------------------------------------------------------------------------
__global__ __launch_bounds__(256) void fft_attn(
    const float* __restrict__ qg, const float* __restrict__ kg, const float* __restrict__ vg,
    bf16* __restrict__ oh, bf16* __restrict__ ol)
{
    __shared__ float re[PD], im[PD], Qr[PD], Qi[PD], Kr[PD], Ki[PD];
    const int tid = threadIdx.x;
    const size_t row = blockIdx.x;
    const float* q = qg + row*PD;
    const float* k = kg + row*PD;
    const float* v = vg + row*PD;

    for (int i = tid; i < PD; i += 256) { re[i] = q[i]; im[i] = 0.f; }
    __syncthreads();
    fft1024(re, im, tid);
    for (int i = tid; i < PD; i += 256) { Qr[i] = re[i]; Qi[i] = im[i]; }
    __syncthreads();

    for (int i = tid; i < PD; i += 256) { re[i] = k[i]; im[i] = 0.f; }
    __syncthreads();
    fft1024(re, im, tid);
    for (int i = tid; i < PD; i += 256) { Kr[i] = re[i]; Ki[i] = im[i]; }
    __syncthreads();

    for (int i = tid; i < PD; i += 256) { re[i] = v[i]; im[i] = 0.f; }
    __syncthreads();
    fft1024(re, im, tid);

    // S = (K * conj(Q)) / 32 * V ; store conj(S) for the forward-FFT inverse trick
    for (int i = tid; i < PD; i += 256) {
        const float c1r = Kr[i]*Qr[i] + Ki[i]*Qi[i];
        const float c1i = Ki[i]*Qr[i] - Kr[i]*Qi[i];
        const float vr = re[i], vi = im[i];
        const float sr = (c1r*vr - c1i*vi) * (1.f/32.f);
        const float si = (c1r*vi + c1i*vr) * (1.f/32.f);
        re[i] = sr; im[i] = -si;
    }
    __syncthreads();
    fft1024(re, im, tid);
    bf16* ph = oh + row*PD;
    bf16* pl = ol + row*PD;
    for (int i = tid; i < PD; i += 256) {
        const float vo = re[i] * (1.f/1024.f);
        const bf16 h = __float2bfloat16(vo);
        ph[i] = h;
        pl[i] = __float2bfloat16(vo - __bfloat162float(h));
    }
}

// ---------------------------------------------------------------------------
extern "C" void kernel_launch(void* const* d_in, const int* in_sizes, int n_in,
                              void* d_out, int out_size, void* d_ws, size_t ws_size,
                              hipStream_t stream)
{
    const float* x      = (const float*)d_in[0];
    const float* conv_w = (const float*)d_in[1];   // [L,E,1,K]
    const float* conv_b = (const float*)d_in[2];   // [L,E]
    const float* wq     = (const float*)d_in[3];   // [L,P,W]
    const float* bq     = (const float*)d_in[4];   // [L,P]
    const float* wk     = (const float*)d_in[5];
    const float* bk     = (const float*)d_in[6];
    const float* wv     = (const float*)d_in[7];
    const float* bv     = (const float*)d_in[8];
    const float* wo     = (const float*)d_in[9];   // [L,W,P]
    const float* bo     = (const float*)d_in[10];  // [L,W]

    // workspace layout (112 MiB total), per-layer weight slots reused:
    //   0M..24M : wq_h,wq_l,wk_h,wk_l,wv_h,wv_l  (6 x 4 MiB, current layer, [P,W] bf16)
    //  24M..32M : wo_h,wo_l                      (2 x 4 MiB, [W,P] bf16)
    //  32M..48M : qbuf f32 [4096,1024]  \  xmid f32 [4096,2048] (32M..64M)
    //  48M..64M : kbuf f32              /  aliases qbuf+kbuf (dead by then)
    //  64M..80M : vbuf f32
    //  80M..96M : xc_hi bf16 [4096,2048] (16 MiB; also wvr_hi [4096,1024] alias)
    //  96M..112M: xc_lo bf16 [4096,2048] (16 MiB; also wvr_lo alias)
    char* ws = (char*)d_ws;
    const size_t MB = 1024*1024;
    bf16*  wqh = (bf16*)(ws);
    bf16*  wql = (bf16*)(ws + 4*MB);
    bf16*  wkh = (bf16*)(ws + 8*MB);
    bf16*  wkl = (bf16*)(ws + 12*MB);
    bf16*  wvh = (bf16*)(ws + 16*MB);
    bf16*  wvl = (bf16*)(ws + 20*MB);
    bf16*  woh = (bf16*)(ws + 24*MB);
    bf16*  wol = (bf16*)(ws + 28*MB);
    float* qbuf = (float*)(ws + 32*MB);
    float* kbuf = (float*)(ws + 48*MB);
    float* vbuf = (float*)(ws + 64*MB);
    float* xmid = (float*)(ws + 32*MB);
    bf16*  xch  = (bf16*)(ws + 80*MB);
    bf16*  xcl  = (bf16*)(ws + 96*MB);
    bf16*  wvrh = xch;   // xc dead once QKV GEMMs complete
    bf16*  wvrl = xcl;

    const int NWL = PD * WD;  // 2M elements per weight tensor per layer
    const dim3 cvtg(NWL/4/256);

    for (int l = 0; l < LN; ++l) {
        // convert this layer's weights to hi/lo bf16 pairs
        cvt_pair<<<cvtg, dim3(256), 0, stream>>>(wq + (size_t)l*NWL, wqh, wql, NWL);
        cvt_pair<<<cvtg, dim3(256), 0, stream>>>(wk + (size_t)l*NWL, wkh, wkl, NWL);
        cvt_pair<<<cvtg, dim3(256), 0, stream>>>(wv + (size_t)l*NWL, wvh, wvl, NWL);
        cvt_pair<<<cvtg, dim3(256), 0, stream>>>(wo + (size_t)l*NWL, woh, wol, NWL);

        const float* xin = (l == 0) ? x : xmid;
        conv_moe<<<dim3(MROWS), dim3(256), 0, stream>>>(
            xin, conv_w + (size_t)l*ED*KSZ, conv_b + (size_t)l*ED, xch, xcl);

        // q,k,v = xc @ w^T + b   (M=4096, K=2048, N=1024), batched via grid.z
        gemm_split3<<<dim3(MROWS/128, PD/128, 3), dim3(256), 0, stream>>>(
            xch, xcl,
            wqh, wql, wkh, wkl, wvh, wvl,
            bq + (size_t)l*PD, bk + (size_t)l*PD, bv + (size_t)l*PD,
            qbuf, kbuf, vbuf, WD, PD);

        fft_attn<<<dim3(MROWS), dim3(256), 0, stream>>>(qbuf, kbuf, vbuf, wvrh, wvrl);

        // xnext = wvr @ wo^T + bo  (M=4096, K=1024, N=2048)
        float* xout = (l == LN-1) ? (float*)d_out : xmid;
        gemm_split3<<<dim3(MROWS/128, WD/128, 1), dim3(256), 0, stream>>>(
            wvrh, wvrl,
            woh, wol, woh, wol, woh, wol,
            bo + (size_t)l*WD, bo + (size_t)l*WD, bo + (size_t)l*WD,
            xout, xout, xout, PD, WD);
    }
}

// Round 5
// 579.047 us; speedup vs baseline: 1.5257x; 1.5257x over previous
//
#include <hip/hip_runtime.h>
#include <hip/hip_bf16.h>

// Problem constants (FEDformerEncoder): BS=32 CNT=128 W=2048 P=1024 E=8 K=25 L=2
#define BSZ 32
#define CNTS 128
#define WD 2048
#define PD 1024
#define ED 8
#define KSZ 25
#define LN 2
#define MROWS (BSZ*CNTS)   // 4096
#define QKVN (3*PD)        // 3072

typedef _Float16 f16;
typedef __attribute__((ext_vector_type(8))) _Float16 f16x8;  // 8 f16 = 4 VGPRs
typedef __attribute__((ext_vector_type(4))) float f32x4;

#define PI_F 3.14159265358979323846f

// ---------------------------------------------------------------------------
// f32 -> f16 conversion (RNE). n multiple of 4.
// ---------------------------------------------------------------------------
__global__ __launch_bounds__(256) void cvt_f16(
    const float* __restrict__ src, f16* __restrict__ dst, int n)
{
    const int i = (blockIdx.x * 256 + threadIdx.x) * 4;
    if (i >= n) return;
    const float4 v = *(const float4*)(src + i);
    f16 o[4];
    o[0] = (f16)v.x; o[1] = (f16)v.y; o[2] = (f16)v.z; o[3] = (f16)v.w;
    *(ushort4*)(dst + i) = *(const ushort4*)o;
}

// ---------------------------------------------------------------------------
// MoE conv: mean over E of conv1d(x, w_e)+b_e == conv1d(x, mean_e w_e)+mean_e b_e
// f32 in, f16 out (A operand for the f16 MFMA GEMM).
// ---------------------------------------------------------------------------
__global__ __launch_bounds__(256) void conv_moe(
    const float* __restrict__ xin,   // [4096, 2048] f32
    const float* __restrict__ cw,    // [E, K] layer slice
    const float* __restrict__ cb,    // [E]
    f16* __restrict__ xo)            // [4096, 2048] f16
{
    __shared__ float srow[WD];
    __shared__ float swb[KSZ];
    __shared__ float sbb;
    const int tid = threadIdx.x;
    const size_t row = blockIdx.x;
    if (tid < KSZ) {
        float s = 0.f;
        for (int e = 0; e < ED; ++e) s += cw[e*KSZ + tid];
        swb[tid] = s * (1.f/ED);
    }
    if (tid == 32) {
        float s = 0.f;
        for (int e = 0; e < ED; ++e) s += cb[e];
        sbb = s * (1.f/ED);
    }
    const float* xr = xin + row*WD;
    for (int i = tid; i < WD; i += 256) srow[i] = xr[i];
    __syncthreads();
    const float bb = sbb;
    for (int t0 = 0; t0 < WD; t0 += 256) {
        const int t = t0 + tid;
        float acc = bb;
        #pragma unroll
        for (int k = 0; k < KSZ; ++k) {
            const int idx = t + k - (KSZ/2);
            const float xv = (idx >= 0 && idx < WD) ? srow[idx] : 0.f;
            acc = fmaf(xv, swb[k], acc);
        }
        xo[row*WD + t] = (f16)acc;
    }
}

// ---------------------------------------------------------------------------
// f16 MFMA GEMM, B^T layout: out[m,n] = sum_k A[m,k]*B[n,k] + bias[n] (f32 out)
// 128x128 tile, BK=32, 256 threads = 4 waves (2x2 of 64x64), m97 structure.
// Bias segmented per 1024 columns (c0: cols 0-1023, c1: 1024-2047, c2: 2048-3071).
// ---------------------------------------------------------------------------
__global__ __launch_bounds__(256, 2) void gemm_f16(
    const f16* __restrict__ A,   // [M, K]
    const f16* __restrict__ B,   // [N, K]
    const float* __restrict__ c0, const float* __restrict__ c1, const float* __restrict__ c2,
    float* __restrict__ out,     // [M, N]
    const int K, const int N)
{
    __shared__ f16 sA[128*32];
    __shared__ f16 sB[128*32];
    const int tid  = threadIdx.x;
    const int m0   = blockIdx.x * 128;
    const int n0   = blockIdx.y * 128;
    const int lane = tid & 63;
    const int wave = tid >> 6;
    const int wm   = (wave >> 1) * 64;
    const int wn   = (wave & 1) * 64;
    const int quad = lane >> 4;
    const int r16  = lane & 15;

    f32x4 acc[4][4] = {};

    // staging chunks: chunk c covers s*[c*8 .. c*8+7] == row (c>>2), cols (c&3)*8..+7
    const int ci0 = tid, ci1 = 256 + tid;
    const int ra0 = ci0 >> 2, ca0 = (ci0 & 3) * 8;
    const int ra1 = ci1 >> 2, ca1 = (ci1 & 3) * 8;

    for (int kb = 0; kb < K; kb += 32) {
        const f16* gA0 = A + (size_t)(m0 + ra0) * K + kb + ca0;
        const f16* gA1 = A + (size_t)(m0 + ra1) * K + kb + ca1;
        const f16* gB0 = B + (size_t)(n0 + ra0) * K + kb + ca0;
        const f16* gB1 = B + (size_t)(n0 + ra1) * K + kb + ca1;
        __builtin_amdgcn_global_load_lds((const __attribute__((address_space(1))) unsigned int*)gA0,
            (__attribute__((address_space(3))) unsigned int*)&sA[ci0*8], 16, 0, 0);
        __builtin_amdgcn_global_load_lds((const __attribute__((address_space(1))) unsigned int*)gA1,
            (__attribute__((address_space(3))) unsigned int*)&sA[ci1*8], 16, 0, 0);
        __builtin_amdgcn_global_load_lds((const __attribute__((address_space(1))) unsigned int*)gB0,
            (__attribute__((address_space(3))) unsigned int*)&sB[ci0*8], 16, 0, 0);
        __builtin_amdgcn_global_load_lds((const __attribute__((address_space(1))) unsigned int*)gB1,
            (__attribute__((address_space(3))) unsigned int*)&sB[ci1*8], 16, 0, 0);
        __syncthreads();

        f16x8 af[4], bfm[4];
        #pragma unroll
        for (int i = 0; i < 4; ++i)
            af[i] = *(const f16x8*)&sA[(wm + i*16 + r16)*32 + quad*8];
        #pragma unroll
        for (int j = 0; j < 4; ++j)
            bfm[j] = *(const f16x8*)&sB[(wn + j*16 + r16)*32 + quad*8];
        #pragma unroll
        for (int i = 0; i < 4; ++i)
            #pragma unroll
            for (int j = 0; j < 4; ++j)
                acc[i][j] = __builtin_amdgcn_mfma_f32_16x16x32_f16(af[i], bfm[j], acc[i][j], 0, 0, 0);
        __syncthreads();
    }

    // epilogue: C/D mapping (16x16x32): col = lane&15, row = quad*4 + r
    #pragma unroll
    for (int j = 0; j < 4; ++j) {
        const int col = n0 + wn + j*16 + r16;
        const float bv = (col < 1024) ? c0[col] : (col < 2048) ? c1[col-1024] : c2[col-2048];
        #pragma unroll
        for (int i = 0; i < 4; ++i) {
            #pragma unroll
            for (int r = 0; r < 4; ++r) {
                const int rowg = m0 + wm + i*16 + quad*4 + r;
                out[(size_t)rowg*N + col] = acc[i][j][r] + bv;
            }
        }
    }
}

// ---------------------------------------------------------------------------
// In-LDS radix-2 DIT FFT, 1024 points, 256 threads, LDS twiddle table.
// twr/twi[j] = W_1024^j = exp(-2*pi*i*j/1024), j in [0,512).
// ---------------------------------------------------------------------------
__device__ inline void fft1024t(float* re, float* im,
                                const float* twr, const float* twi, const int tid)
{
    for (int i = tid; i < 1024; i += 256) {
        const int j = __brev((unsigned)i) >> 22;
        if (i < j) {
            float t = re[i]; re[i] = re[j]; re[j] = t;
            t = im[i]; im[i] = im[j]; im[j] = t;
        }
    }
    __syncthreads();
    for (int s = 1; s <= 10; ++s) {
        const int half = 1 << (s - 1);
        const int shift = 10 - s;
        for (int t = tid; t < 512; t += 256) {
            const int pos = t & (half - 1);
            const int i = ((t >> (s - 1)) << s) + pos;
            const int j = i + half;
            const int ti = pos << shift;
            const float wr = twr[ti], wi = twi[ti];
            const float xr = re[j], xi = im[j];
            const float tr = wr*xr - wi*xi;
            const float tii = wr*xi + wi*xr;
            const float ur = re[i], ui = im[i];
            re[j] = ur - tr; im[j] = ui - tii;
            re[i] = ur + tr; im[i] = ui + tii;
        }
        __syncthreads();
    }
}

// ---------------------------------------------------------------------------
// FFT-domain attention, two rows per block, packed-real FFTs:
//   wv = ifft( fft(k) * conj(fft(q)) / 32 * fft(v) ).real
// Per row-pair: FFT(v1+i*v2) -> split V1,V2 (Hermitian split);
//               FFT(q1+i*k1) -> split Q1,K1 -> T1 = conj(K1*conj(Q1)*V1/32);
//               FFT(q2+i*k2) -> T2;
//               FFT(T1 + i*T2) = N*wv1 + i*N*wv2  (fft(conj(S)) real for Hermitian S).
// Inputs from interleaved qkv buffer [rows, 3072] (q|k|v). f16 output.
// ---------------------------------------------------------------------------
__global__ __launch_bounds__(256) void fft_attn2(
    const float* __restrict__ qkv, f16* __restrict__ outg)
{
    __shared__ float zr[PD], zi[PD];   // FFT workspace
    __shared__ float ar[PD], ai[PD];   // V1, then conj(S1)
    __shared__ float br[PD], bi[PD];   // V2, then conj(S2)
    __shared__ float twr[512], twi[512];
    const int tid = threadIdx.x;
    const size_t row0 = (size_t)blockIdx.x * 2;
    const float* r1 = qkv + row0*QKVN;        // q1 | k1 | v1
    const float* r2 = qkv + (row0+1)*QKVN;    // q2 | k2 | v2

    for (int j = tid; j < 512; j += 256) {
        float s, c;
        __sincosf(-2.f*PI_F*j*(1.f/1024.f), &s, &c);
        twr[j] = c; twi[j] = s;
    }
    // (twiddle writes are covered by the bit-reversal barrier inside fft1024t)

    // ---- FFT of v1 + i*v2 ----
    for (int i = tid; i < PD; i += 256) { zr[i] = r1[2048+i]; zi[i] = r2[2048+i]; }
    __syncthreads();
    fft1024t(zr, zi, twr, twi, tid);
    for (int f = tid; f < PD; f += 256) {
        const int g = (PD - f) & (PD-1);
        const float x1 = zr[f], y1 = zi[f], x2 = zr[g], y2 = zi[g];
        ar[f] = 0.5f*(x1+x2); ai[f] = 0.5f*(y1-y2);      // V1
        br[f] = 0.5f*(y1+y2); bi[f] = 0.5f*(x2-x1);      // V2
    }
    __syncthreads();

    // ---- FFT of q1 + i*k1 ; T1 = conj(K1*conj(Q1)*V1/32) ----
    for (int i = tid; i < PD; i += 256) { zr[i] = r1[i]; zi[i] = r1[1024+i]; }
    __syncthreads();
    fft1024t(zr, zi, twr, twi, tid);
    for (int f = tid; f < PD; f += 256) {
        const int g = (PD - f) & (PD-1);
        const float x1 = zr[f], y1 = zi[f], x2 = zr[g], y2 = zi[g];
        const float Qr = 0.5f*(x1+x2), Qi = 0.5f*(y1-y2);
        const float Kr = 0.5f*(y1+y2), Ki = 0.5f*(x2-x1);
        const float Pr = (Kr*Qr + Ki*Qi) * (1.f/32.f);
        const float Pi = (Ki*Qr - Kr*Qi) * (1.f/32.f);
        const float Vr = ar[f], Vi = ai[f];
        ar[f] = Pr*Vr - Pi*Vi;
        ai[f] = -(Pr*Vi + Pi*Vr);
    }
    __syncthreads();

    // ---- FFT of q2 + i*k2 ; T2 = conj(K2*conj(Q2)*V2/32) ----
    for (int i = tid; i < PD; i += 256) { zr[i] = r2[i]; zi[i] = r2[1024+i]; }
    __syncthreads();
    fft1024t(zr, zi, twr, twi, tid);
    for (int f = tid; f < PD; f += 256) {
        const int g = (PD - f) & (PD-1);
        const float x1 = zr[f], y1 = zi[f], x2 = zr[g], y2 = zi[g];
        const float Qr = 0.5f*(x1+x2), Qi = 0.5f*(y1-y2);
        const float Kr = 0.5f*(y1+y2), Ki = 0.5f*(x2-x1);
        const float Pr = (Kr*Qr + Ki*Qi) * (1.f/32.f);
        const float Pi = (Ki*Qr - Kr*Qi) * (1.f/32.f);
        const float Vr = br[f], Vi = bi[f];
        br[f] = Pr*Vr - Pi*Vi;
        bi[f] = -(Pr*Vi + Pi*Vr);
    }
    __syncthreads();

    // ---- packed inverse: FFT(T1 + i*T2) ----
    for (int f = tid; f < PD; f += 256) {
        zr[f] = ar[f] - bi[f];
        zi[f] = ai[f] + br[f];
    }
    __syncthreads();
    fft1024t(zr, zi, twr, twi, tid);
    f16* o1 = outg + row0*PD;
    f16* o2 = o1 + PD;
    for (int n = tid; n < PD; n += 256) {
        o1[n] = (f16)(zr[n] * (1.f/1024.f));
        o2[n] = (f16)(zi[n] * (1.f/1024.f));
    }
}

// ---------------------------------------------------------------------------
extern "C" void kernel_launch(void* const* d_in, const int* in_sizes, int n_in,
                              void* d_out, int out_size, void* d_ws, size_t ws_size,
                              hipStream_t stream)
{
    const float* x      = (const float*)d_in[0];
    const float* conv_w = (const float*)d_in[1];   // [L,E,1,K]
    const float* conv_b = (const float*)d_in[2];   // [L,E]
    const float* wq     = (const float*)d_in[3];   // [L,P,W]
    const float* bq     = (const float*)d_in[4];   // [L,P]
    const float* wk     = (const float*)d_in[5];
    const float* bk     = (const float*)d_in[6];
    const float* wv     = (const float*)d_in[7];
    const float* bv     = (const float*)d_in[8];
    const float* wo     = (const float*)d_in[9];   // [L,W,P]
    const float* bo     = (const float*)d_in[10];  // [L,W]

    // workspace layout (112 MiB), per-layer weight slots reused:
    //   0M..12M : wqkv16 f16 [3072, 2048]  (q rows 0-1023, k 1024-2047, v 2048-3071)
    //  12M..16M : wo16   f16 [2048, 1024]
    //  16M..64M : qkvbuf f32 [4096, 3072]  (row-interleaved q|k|v)
    //  64M..96M : xmid   f32 [4096, 2048]
    //  96M..112M: xc16   f16 [4096, 2048]  (first 8 MiB also aliased as wvr16 [4096,1024])
    char* ws = (char*)d_ws;
    const size_t MB = 1024*1024;
    f16*   wqkv16 = (f16*)(ws);
    f16*   wo16   = (f16*)(ws + 12*MB);
    float* qkvbuf = (float*)(ws + 16*MB);
    float* xmid   = (float*)(ws + 64*MB);
    f16*   xc16   = (f16*)(ws + 96*MB);
    f16*   wvr16  = xc16;   // alias: xc dead once the QKV GEMM completes

    const int NWL = PD * WD;  // 2M elements per weight tensor per layer
    const dim3 cvtg(NWL/4/256);

    for (int l = 0; l < LN; ++l) {
        // convert this layer's weights to f16 (qkv packed along N)
        cvt_f16<<<cvtg, dim3(256), 0, stream>>>(wq + (size_t)l*NWL, wqkv16,              NWL);
        cvt_f16<<<cvtg, dim3(256), 0, stream>>>(wk + (size_t)l*NWL, wqkv16 + (size_t)PD*WD,   NWL);
        cvt_f16<<<cvtg, dim3(256), 0, stream>>>(wv + (size_t)l*NWL, wqkv16 + (size_t)2*PD*WD, NWL);
        cvt_f16<<<cvtg, dim3(256), 0, stream>>>(wo + (size_t)l*NWL, wo16, NWL);

        const float* xin = (l == 0) ? x : xmid;
        conv_moe<<<dim3(MROWS), dim3(256), 0, stream>>>(
            xin, conv_w + (size_t)l*ED*KSZ, conv_b + (size_t)l*ED, xc16);

        // qkv = xc @ wqkv^T + [bq|bk|bv]   (M=4096, K=2048, N=3072)
        gemm_f16<<<dim3(MROWS/128, QKVN/128), dim3(256), 0, stream>>>(
            xc16, wqkv16,
            bq + (size_t)l*PD, bk + (size_t)l*PD, bv + (size_t)l*PD,
            qkvbuf, WD, QKVN);

        fft_attn2<<<dim3(MROWS/2), dim3(256), 0, stream>>>(qkvbuf, wvr16);

        // xnext = wvr @ wo^T + bo  (M=4096, K=1024, N=2048)
        float* xout = (l == LN-1) ? (float*)d_out : xmid;
        gemm_f16<<<dim3(MROWS/128, WD/128), dim3(256), 0, stream>>>(
            wvr16, wo16,
            bo + (size_t)l*WD, bo + (size_t)l*WD + PD, bo + (size_t)l*WD + PD,
            xout, PD, WD);
    }
}

// Round 6
// 439.055 us; speedup vs baseline: 2.0121x; 1.3188x over previous
//
#include <hip/hip_runtime.h>
#include <hip/hip_bf16.h>

// Problem constants (FEDformerEncoder): BS=32 CNT=128 W=2048 P=1024 E=8 K=25 L=2
#define BSZ 32
#define CNTS 128
#define WD 2048
#define PD 1024
#define ED 8
#define KSZ 25
#define LN 2
#define MROWS (BSZ*CNTS)   // 4096
#define QKVN (3*PD)        // 3072

typedef _Float16 f16;
typedef __attribute__((ext_vector_type(8))) _Float16 f16x8;  // 8 f16 = 4 VGPRs
typedef __attribute__((ext_vector_type(4))) float f32x4;
typedef __attribute__((ext_vector_type(2))) float f32x2;

#define PI_F 3.14159265358979323846f
// LDS physical index padding: +1 float2 per 32 elements (dodges pow-2 stride conflicts)
#define PAD(a) ((a) + ((a) >> 5))

// ---------------------------------------------------------------------------
// f32 -> f16 conversion (RNE). n multiple of 4.
// ---------------------------------------------------------------------------
__global__ __launch_bounds__(256) void cvt_f16(
    const float* __restrict__ src, f16* __restrict__ dst, int n)
{
    const int i = (blockIdx.x * 256 + threadIdx.x) * 4;
    if (i >= n) return;
    const float4 v = *(const float4*)(src + i);
    f16 o[4];
    o[0] = (f16)v.x; o[1] = (f16)v.y; o[2] = (f16)v.z; o[3] = (f16)v.w;
    *(ushort4*)(dst + i) = *(const ushort4*)o;
}

// ---------------------------------------------------------------------------
// MoE conv: mean over E of conv1d(x, w_e)+b_e == conv1d(x, mean_e w_e)+mean_e b_e
// f32 in, f16 out (A operand for the f16 MFMA GEMM).
// ---------------------------------------------------------------------------
__global__ __launch_bounds__(256) void conv_moe(
    const float* __restrict__ xin,   // [4096, 2048] f32
    const float* __restrict__ cw,    // [E, K] layer slice
    const float* __restrict__ cb,    // [E]
    f16* __restrict__ xo)            // [4096, 2048] f16
{
    __shared__ float srow[WD];
    __shared__ float swb[KSZ];
    __shared__ float sbb;
    const int tid = threadIdx.x;
    const size_t row = blockIdx.x;
    if (tid < KSZ) {
        float s = 0.f;
        for (int e = 0; e < ED; ++e) s += cw[e*KSZ + tid];
        swb[tid] = s * (1.f/ED);
    }
    if (tid == 32) {
        float s = 0.f;
        for (int e = 0; e < ED; ++e) s += cb[e];
        sbb = s * (1.f/ED);
    }
    const float* xr = xin + row*WD;
    for (int i = tid; i < WD; i += 256) srow[i] = xr[i];
    __syncthreads();
    const float bb = sbb;
    for (int t0 = 0; t0 < WD; t0 += 256) {
        const int t = t0 + tid;
        float acc = bb;
        #pragma unroll
        for (int k = 0; k < KSZ; ++k) {
            const int idx = t + k - (KSZ/2);
            const float xv = (idx >= 0 && idx < WD) ? srow[idx] : 0.f;
            acc = fmaf(xv, swb[k], acc);
        }
        xo[row*WD + t] = (f16)acc;
    }
}

// ---------------------------------------------------------------------------
// f16 MFMA GEMM, B^T layout: out[m,n] = sum_k A[m,k]*B[n,k] + bias[n] (f32 out)
// 128x128 tile, BK=32, 256 threads = 4 waves (2x2 of 64x64), m97 structure.
// Bias segmented per 1024 columns (c0: cols 0-1023, c1: 1024-2047, c2: 2048-3071).
// ---------------------------------------------------------------------------
__global__ __launch_bounds__(256, 2) void gemm_f16(
    const f16* __restrict__ A,   // [M, K]
    const f16* __restrict__ B,   // [N, K]
    const float* __restrict__ c0, const float* __restrict__ c1, const float* __restrict__ c2,
    float* __restrict__ out,     // [M, N]
    const int K, const int N)
{
    __shared__ f16 sA[128*32];
    __shared__ f16 sB[128*32];
    const int tid  = threadIdx.x;
    const int m0   = blockIdx.x * 128;
    const int n0   = blockIdx.y * 128;
    const int lane = tid & 63;
    const int wave = tid >> 6;
    const int wm   = (wave >> 1) * 64;
    const int wn   = (wave & 1) * 64;
    const int quad = lane >> 4;
    const int r16  = lane & 15;

    f32x4 acc[4][4] = {};

    // staging chunks: chunk c covers s*[c*8 .. c*8+7] == row (c>>2), cols (c&3)*8..+7
    const int ci0 = tid, ci1 = 256 + tid;
    const int ra0 = ci0 >> 2, ca0 = (ci0 & 3) * 8;
    const int ra1 = ci1 >> 2, ca1 = (ci1 & 3) * 8;

    for (int kb = 0; kb < K; kb += 32) {
        const f16* gA0 = A + (size_t)(m0 + ra0) * K + kb + ca0;
        const f16* gA1 = A + (size_t)(m0 + ra1) * K + kb + ca1;
        const f16* gB0 = B + (size_t)(n0 + ra0) * K + kb + ca0;
        const f16* gB1 = B + (size_t)(n0 + ra1) * K + kb + ca1;
        __builtin_amdgcn_global_load_lds((const __attribute__((address_space(1))) unsigned int*)gA0,
            (__attribute__((address_space(3))) unsigned int*)&sA[ci0*8], 16, 0, 0);
        __builtin_amdgcn_global_load_lds((const __attribute__((address_space(1))) unsigned int*)gA1,
            (__attribute__((address_space(3))) unsigned int*)&sA[ci1*8], 16, 0, 0);
        __builtin_amdgcn_global_load_lds((const __attribute__((address_space(1))) unsigned int*)gB0,
            (__attribute__((address_space(3))) unsigned int*)&sB[ci0*8], 16, 0, 0);
        __builtin_amdgcn_global_load_lds((const __attribute__((address_space(1))) unsigned int*)gB1,
            (__attribute__((address_space(3))) unsigned int*)&sB[ci1*8], 16, 0, 0);
        __syncthreads();

        f16x8 af[4], bfm[4];
        #pragma unroll
        for (int i = 0; i < 4; ++i)
            af[i] = *(const f16x8*)&sA[(wm + i*16 + r16)*32 + quad*8];
        #pragma unroll
        for (int j = 0; j < 4; ++j)
            bfm[j] = *(const f16x8*)&sB[(wn + j*16 + r16)*32 + quad*8];
        #pragma unroll
        for (int i = 0; i < 4; ++i)
            #pragma unroll
            for (int j = 0; j < 4; ++j)
                acc[i][j] = __builtin_amdgcn_mfma_f32_16x16x32_f16(af[i], bfm[j], acc[i][j], 0, 0, 0);
        __syncthreads();
    }

    // epilogue: C/D mapping (16x16x32): col = lane&15, row = quad*4 + r
    #pragma unroll
    for (int j = 0; j < 4; ++j) {
        const int col = n0 + wn + j*16 + r16;
        const float bv = (col < 1024) ? c0[col] : (col < 2048) ? c1[col-1024] : c2[col-2048];
        #pragma unroll
        for (int i = 0; i < 4; ++i) {
            #pragma unroll
            for (int r = 0; r < 4; ++r) {
                const int rowg = m0 + wm + i*16 + quad*4 + r;
                out[(size_t)rowg*N + col] = acc[i][j][r] + bv;
            }
        }
    }
}

// ---------------------------------------------------------------------------
// Stockham radix-4 DIF FFT, 1024 points, 256 threads, interleaved f32x2 in LDS
// with PAD() physical indexing. No bit-reversal; 5 stages, 1 barrier/stage.
// Input in x (PAD layout), output lands in y (PAD layout). Verified at N=4/16:
//   stage (n,s): reads src[t + k*256], k=0..3;  p=t>>log2(s), q=t&(s-1)
//   y0=(a+c)+(b+d); y1=w1*((a-c)-i(b-d)); y2=w2*((a+c)-(b+d)); y3=w3*((a-c)+i(b-d))
//   writes dst[q + 4sp + v*s]; w1=exp(-2*pi*i*p/n)
// ---------------------------------------------------------------------------
__device__ inline void fft1024r4(f32x2* x, f32x2* y, const int tid)
{
    f32x2* src = x;
    f32x2* dst = y;
    #pragma unroll
    for (int st = 0; st < 5; ++st) {
        const int ls = 2*st;
        const int s  = 1 << ls;
        const int p  = tid >> ls;
        const int q  = tid & (s - 1);
        const float invn = 1.f / (float)(1024 >> ls);
        const f32x2 a = src[PAD(tid)];
        const f32x2 b = src[PAD(tid + 256)];
        const f32x2 c = src[PAD(tid + 512)];
        const f32x2 d = src[PAD(tid + 768)];
        float ws, wc;
        __sincosf(-2.f*PI_F * (float)p * invn, &ws, &wc);
        const float apcx = a.x + c.x, apcy = a.y + c.y;
        const float amcx = a.x - c.x, amcy = a.y - c.y;
        const float bpdx = b.x + d.x, bpdy = b.y + d.y;
        const float bmdx = b.x - d.x, bmdy = b.y - d.y;
        f32x2 y0; y0.x = apcx + bpdx; y0.y = apcy + bpdy;
        const float t1x = amcx + bmdy, t1y = amcy - bmdx;   // amc - i*bmd
        const float t2x = apcx - bpdx, t2y = apcy - bpdy;
        const float t3x = amcx - bmdy, t3y = amcy + bmdx;   // amc + i*bmd
        const float w2x = wc*wc - ws*ws, w2y = 2.f*wc*ws;
        const float w3x = w2x*wc - w2y*ws, w3y = w2x*ws + w2y*wc;
        f32x2 y1; y1.x = wc*t1x - ws*t1y;   y1.y = wc*t1y + ws*t1x;
        f32x2 y2; y2.x = w2x*t2x - w2y*t2y; y2.y = w2x*t2y + w2y*t2x;
        f32x2 y3; y3.x = w3x*t3x - w3y*t3y; y3.y = w3x*t3y + w3y*t3x;
        const int base = q + ((p * s) << 2);
        dst[PAD(base)]       = y0;
        dst[PAD(base + s)]   = y1;
        dst[PAD(base + 2*s)] = y2;
        dst[PAD(base + 3*s)] = y3;
        __syncthreads();
        f32x2* t = src; src = dst; dst = t;
    }
}

// ---------------------------------------------------------------------------
// FFT-domain attention, two rows per block, packed-real FFTs:
//   wv = ifft( fft(k) * conj(fft(q)) / 32 * fft(v) ).real
// Per row-pair: FFT(v1+i*v2) -> split V1,V2 into REGISTERS (Hermitian split);
//               FFT(q1+i*k1) -> T1 = conj(K1*conj(Q1)*V1/32) in regs;
//               FFT(q2+i*k2) -> T2 in regs;
//               FFT(T1 + i*T2) = N*wv1 + i*N*wv2.
// Inputs from interleaved qkv buffer [rows, 3072] (q|k|v). f16 output.
// ---------------------------------------------------------------------------
__global__ __launch_bounds__(256) void fft_attn2(
    const float* __restrict__ qkv, f16* __restrict__ outg)
{
    __shared__ f32x2 X[PAD(1023)+1], Y[PAD(1023)+1];
    const int tid = threadIdx.x;
    const size_t row0 = (size_t)blockIdx.x * 2;
    const float* r1 = qkv + row0*QKVN;        // q1 | k1 | v1
    const float* r2 = r1 + QKVN;              // q2 | k2 | v2

    f32x2 V1[4], V2[4], S1[4], S2[4];

    // ---- FFT(v1 + i*v2) -> V1, V2 in registers ----
    #pragma unroll
    for (int k = 0; k < 4; ++k) {
        const int i = tid + 256*k;
        f32x2 t; t.x = r1[2048+i]; t.y = r2[2048+i];
        X[PAD(i)] = t;
    }
    __syncthreads();
    fft1024r4(X, Y, tid);
    #pragma unroll
    for (int k = 0; k < 4; ++k) {
        const int f = tid + 256*k;
        const int g = (PD - f) & (PD-1);
        const f32x2 z1 = Y[PAD(f)], z2 = Y[PAD(g)];
        V1[k].x = 0.5f*(z1.x + z2.x); V1[k].y = 0.5f*(z1.y - z2.y);
        V2[k].x = 0.5f*(z1.y + z2.y); V2[k].y = 0.5f*(z2.x - z1.x);
    }

    // ---- FFT(q1 + i*k1) ; S1 = conj(K1*conj(Q1)*V1/32) ----
    #pragma unroll
    for (int k = 0; k < 4; ++k) {
        const int i = tid + 256*k;
        f32x2 t; t.x = r1[i]; t.y = r1[1024+i];
        X[PAD(i)] = t;
    }
    __syncthreads();   // also fences the V-split reads of Y above
    fft1024r4(X, Y, tid);
    #pragma unroll
    for (int k = 0; k < 4; ++k) {
        const int f = tid + 256*k;
        const int g = (PD - f) & (PD-1);
        const f32x2 z1 = Y[PAD(f)], z2 = Y[PAD(g)];
        const float Qr = 0.5f*(z1.x + z2.x), Qi = 0.5f*(z1.y - z2.y);
        const float Kr = 0.5f*(z1.y + z2.y), Ki = 0.5f*(z2.x - z1.x);
        const float Pr = (Kr*Qr + Ki*Qi) * (1.f/32.f);
        const float Pi = (Ki*Qr - Kr*Qi) * (1.f/32.f);
        S1[k].x = Pr*V1[k].x - Pi*V1[k].y;
        S1[k].y = -(Pr*V1[k].y + Pi*V1[k].x);
    }

    // ---- FFT(q2 + i*k2) ; S2 = conj(K2*conj(Q2)*V2/32) ----
    #pragma unroll
    for (int k = 0; k < 4; ++k) {
        const int i = tid + 256*k;
        f32x2 t; t.x = r2[i]; t.y = r2[1024+i];
        X[PAD(i)] = t;
    }
    __syncthreads();
    fft1024r4(X, Y, tid);
    #pragma unroll
    for (int k = 0; k < 4; ++k) {
        const int f = tid + 256*k;
        const int g = (PD - f) & (PD-1);
        const f32x2 z1 = Y[PAD(f)], z2 = Y[PAD(g)];
        const float Qr = 0.5f*(z1.x + z2.x), Qi = 0.5f*(z1.y - z2.y);
        const float Kr = 0.5f*(z1.y + z2.y), Ki = 0.5f*(z2.x - z1.x);
        const float Pr = (Kr*Qr + Ki*Qi) * (1.f/32.f);
        const float Pi = (Ki*Qr - Kr*Qi) * (1.f/32.f);
        S2[k].x = Pr*V2[k].x - Pi*V2[k].y;
        S2[k].y = -(Pr*V2[k].y + Pi*V2[k].x);
    }

    // ---- packed inverse: FFT(S1 + i*S2) ----
    #pragma unroll
    for (int k = 0; k < 4; ++k) {
        const int f = tid + 256*k;
        f32x2 t; t.x = S1[k].x - S2[k].y; t.y = S1[k].y + S2[k].x;
        X[PAD(f)] = t;
    }
    __syncthreads();
    fft1024r4(X, Y, tid);
    f16* o1 = outg + row0*PD;
    f16* o2 = o1 + PD;
    #pragma unroll
    for (int k = 0; k < 4; ++k) {
        const int n = tid + 256*k;
        const f32x2 z = Y[PAD(n)];
        o1[n] = (f16)(z.x * (1.f/1024.f));
        o2[n] = (f16)(z.y * (1.f/1024.f));
    }
}

// ---------------------------------------------------------------------------
extern "C" void kernel_launch(void* const* d_in, const int* in_sizes, int n_in,
                              void* d_out, int out_size, void* d_ws, size_t ws_size,
                              hipStream_t stream)
{
    const float* x      = (const float*)d_in[0];
    const float* conv_w = (const float*)d_in[1];   // [L,E,1,K]
    const float* conv_b = (const float*)d_in[2];   // [L,E]
    const float* wq     = (const float*)d_in[3];   // [L,P,W]
    const float* bq     = (const float*)d_in[4];   // [L,P]
    const float* wk     = (const float*)d_in[5];
    const float* bk     = (const float*)d_in[6];
    const float* wv     = (const float*)d_in[7];
    const float* bv     = (const float*)d_in[8];
    const float* wo     = (const float*)d_in[9];   // [L,W,P]
    const float* bo     = (const float*)d_in[10];  // [L,W]

    // workspace layout (112 MiB), per-layer weight slots reused:
    //   0M..12M : wqkv16 f16 [3072, 2048]  (q rows 0-1023, k 1024-2047, v 2048-3071)
    //  12M..16M : wo16   f16 [2048, 1024]
    //  16M..64M : qkvbuf f32 [4096, 3072]  (row-interleaved q|k|v)
    //  64M..96M : xmid   f32 [4096, 2048]
    //  96M..112M: xc16   f16 [4096, 2048]  (first 8 MiB also aliased as wvr16 [4096,1024])
    char* ws = (char*)d_ws;
    const size_t MB = 1024*1024;
    f16*   wqkv16 = (f16*)(ws);
    f16*   wo16   = (f16*)(ws + 12*MB);
    float* qkvbuf = (float*)(ws + 16*MB);
    float* xmid   = (float*)(ws + 64*MB);
    f16*   xc16   = (f16*)(ws + 96*MB);
    f16*   wvr16  = xc16;   // alias: xc dead once the QKV GEMM completes

    const int NWL = PD * WD;  // 2M elements per weight tensor per layer
    const dim3 cvtg(NWL/4/256);

    for (int l = 0; l < LN; ++l) {
        // convert this layer's weights to f16 (qkv packed along N)
        cvt_f16<<<cvtg, dim3(256), 0, stream>>>(wq + (size_t)l*NWL, wqkv16,                   NWL);
        cvt_f16<<<cvtg, dim3(256), 0, stream>>>(wk + (size_t)l*NWL, wqkv16 + (size_t)PD*WD,   NWL);
        cvt_f16<<<cvtg, dim3(256), 0, stream>>>(wv + (size_t)l*NWL, wqkv16 + (size_t)2*PD*WD, NWL);
        cvt_f16<<<cvtg, dim3(256), 0, stream>>>(wo + (size_t)l*NWL, wo16, NWL);

        const float* xin = (l == 0) ? x : xmid;
        conv_moe<<<dim3(MROWS), dim3(256), 0, stream>>>(
            xin, conv_w + (size_t)l*ED*KSZ, conv_b + (size_t)l*ED, xc16);

        // qkv = xc @ wqkv^T + [bq|bk|bv]   (M=4096, K=2048, N=3072)
        gemm_f16<<<dim3(MROWS/128, QKVN/128), dim3(256), 0, stream>>>(
            xc16, wqkv16,
            bq + (size_t)l*PD, bk + (size_t)l*PD, bv + (size_t)l*PD,
            qkvbuf, WD, QKVN);

        fft_attn2<<<dim3(MROWS/2), dim3(256), 0, stream>>>(qkvbuf, wvr16);

        // xnext = wvr @ wo^T + bo  (M=4096, K=1024, N=2048)
        float* xout = (l == LN-1) ? (float*)d_out : xmid;
        gemm_f16<<<dim3(MROWS/128, WD/128), dim3(256), 0, stream>>>(
            wvr16, wo16,
            bo + (size_t)l*WD, bo + (size_t)l*WD + PD, bo + (size_t)l*WD + PD,
            xout, PD, WD);
    }
}

// Round 7
// 413.864 us; speedup vs baseline: 2.1346x; 1.0609x over previous
//
#include <hip/hip_runtime.h>
#include <hip/hip_bf16.h>

// Problem constants (FEDformerEncoder): BS=32 CNT=128 W=2048 P=1024 E=8 K=25 L=2
#define BSZ 32
#define CNTS 128
#define WD 2048
#define PD 1024
#define ED 8
#define KSZ 25
#define LN 2
#define MROWS (BSZ*CNTS)   // 4096
#define QKVN (3*PD)        // 3072
#define NWL (PD*WD)        // 2M elements per weight tensor per layer

typedef _Float16 f16;
typedef __attribute__((ext_vector_type(8))) _Float16 f16x8;  // 8 f16 = 4 VGPRs
typedef __attribute__((ext_vector_type(4))) float f32x4;
typedef __attribute__((ext_vector_type(2))) float f32x2;

#define PI_F 3.14159265358979323846f
// LDS physical index padding for the FFT (+1 float2 per 32 elements)
#define PAD(a) ((a) + ((a) >> 5))

// ---------------------------------------------------------------------------
// Per-layer weight conversion, one dispatch: wq|wk|wv -> wqkv16 packed, wo -> wo16.
// ---------------------------------------------------------------------------
__global__ __launch_bounds__(256) void cvt_layer(
    const float* __restrict__ wq, const float* __restrict__ wk,
    const float* __restrict__ wv, const float* __restrict__ wo,
    f16* __restrict__ wqkv16, f16* __restrict__ wo16)
{
    const int i = (blockIdx.x * 256 + threadIdx.x) * 4;
    const float* src;
    f16* dst;
    if (i < 3*NWL) {
        dst = wqkv16 + i;
        src = (i < NWL) ? wq + i : (i < 2*NWL) ? wk + (i - NWL) : wv + (i - 2*NWL);
    } else {
        dst = wo16 + (i - 3*NWL);
        src = wo + (i - 3*NWL);
    }
    const float4 v = *(const float4*)src;
    f16 o[4];
    o[0] = (f16)v.x; o[1] = (f16)v.y; o[2] = (f16)v.z; o[3] = (f16)v.w;
    *(ushort4*)dst = *(const ushort4*)o;
}

// ---------------------------------------------------------------------------
// MoE conv: mean over E of conv1d(x, w_e)+b_e == conv1d(x, mean_e w_e)+mean_e b_e
// IT in (f32 layer 0, f16 layer 1), f16 out (A operand for the f16 MFMA GEMM).
// ---------------------------------------------------------------------------
template<typename IT>
__global__ __launch_bounds__(256) void conv_moe(
    const IT* __restrict__ xin,      // [4096, 2048]
    const float* __restrict__ cw,    // [E, K] layer slice
    const float* __restrict__ cb,    // [E]
    f16* __restrict__ xo)            // [4096, 2048] f16
{
    __shared__ float srow[WD];
    __shared__ float swb[KSZ];
    __shared__ float sbb;
    const int tid = threadIdx.x;
    const size_t row = blockIdx.x;
    if (tid < KSZ) {
        float s = 0.f;
        for (int e = 0; e < ED; ++e) s += cw[e*KSZ + tid];
        swb[tid] = s * (1.f/ED);
    }
    if (tid == 32) {
        float s = 0.f;
        for (int e = 0; e < ED; ++e) s += cb[e];
        sbb = s * (1.f/ED);
    }
    const IT* xr = xin + row*WD;
    for (int i = tid; i < WD; i += 256) srow[i] = (float)xr[i];
    __syncthreads();
    const float bb = sbb;
    for (int t0 = 0; t0 < WD; t0 += 256) {
        const int t = t0 + tid;
        float acc = bb;
        #pragma unroll
        for (int k = 0; k < KSZ; ++k) {
            const int idx = t + k - (KSZ/2);
            const float xv = (idx >= 0 && idx < WD) ? srow[idx] : 0.f;
            acc = fmaf(xv, swb[k], acc);
        }
        xo[row*WD + t] = (f16)acc;
    }
}

// ---------------------------------------------------------------------------
// f16 MFMA GEMM, B^T layout: out[m,n] = sum_k A[m,k]*B[n,k] + bias[n]
// 128x128 tile, BK=64, 256 threads = 4 waves (2x2 of 64x64).
// XOR-swizzled LDS staging: LDS slot s (1024 per matrix, 16B chunks) holds the
// global chunk (s&7)^(row&7) of row s>>3 -> conflict-free ds_read_b128 while
// keeping global_load_lds's wave-uniform-base + lane*16 destination rule.
// Bias segmented per 1024 columns. OT = f16 or f32 output.
// ---------------------------------------------------------------------------
template<typename OT>
__global__ __launch_bounds__(256, 2) void gemm_f16(
    const f16* __restrict__ A,   // [M, K]
    const f16* __restrict__ B,   // [N, K]
    const float* __restrict__ c0, const float* __restrict__ c1, const float* __restrict__ c2,
    OT* __restrict__ out,        // [M, N]
    const int K, const int N)
{
    __shared__ f16 sA[128*64];
    __shared__ f16 sB[128*64];
    const int tid  = threadIdx.x;
    const int m0   = blockIdx.x * 128;
    const int n0   = blockIdx.y * 128;
    const int lane = tid & 63;
    const int wave = tid >> 6;
    const int wm   = (wave >> 1) * 64;
    const int wn   = (wave & 1) * 64;
    const int quad = lane >> 4;
    const int r16  = lane & 15;

    f32x4 acc[4][4] = {};

    // staging: 4 slots/thread; slot s -> row s>>3, source chunk (s&7)^(row&7)
    int arow[4], aoff[4];
    #pragma unroll
    for (int t = 0; t < 4; ++t) {
        const int s = tid + 256*t;
        const int row = s >> 3;
        const int sc8 = ((s & 7) ^ (row & 7)) * 8;
        arow[t] = row;
        aoff[t] = row * K + sc8;   // add m0*K / n0*K + kb at use
    }

    // read-side slot bases: row r -> slot base (r<<3), xor key (r&7)
    int aBase[4], aXor[4], bBase[4], bXor[4];
    #pragma unroll
    for (int i = 0; i < 4; ++i) {
        const int ra = wm + i*16 + r16;
        aBase[i] = ra << 3; aXor[i] = ra & 7;
        const int rb = wn + i*16 + r16;
        bBase[i] = rb << 3; bXor[i] = rb & 7;
    }

    const size_t mK = (size_t)m0 * K;
    const size_t nK = (size_t)n0 * K;

    for (int kb = 0; kb < K; kb += 64) {
        #pragma unroll
        for (int t = 0; t < 4; ++t) {
            const int s = tid + 256*t;
            __builtin_amdgcn_global_load_lds(
                (const __attribute__((address_space(1))) unsigned int*)(A + mK + aoff[t] + kb),
                (__attribute__((address_space(3))) unsigned int*)&sA[s*8], 16, 0, 0);
            __builtin_amdgcn_global_load_lds(
                (const __attribute__((address_space(1))) unsigned int*)(B + nK + aoff[t] + kb),
                (__attribute__((address_space(3))) unsigned int*)&sB[s*8], 16, 0, 0);
        }
        __syncthreads();

        #pragma unroll
        for (int ks = 0; ks < 2; ++ks) {
            const int c = ks*4 + quad;
            f16x8 af[4], bfm[4];
            #pragma unroll
            for (int i = 0; i < 4; ++i)
                af[i] = *(const f16x8*)&sA[(aBase[i] | (c ^ aXor[i])) * 8];
            #pragma unroll
            for (int j = 0; j < 4; ++j)
                bfm[j] = *(const f16x8*)&sB[(bBase[j] | (c ^ bXor[j])) * 8];
            #pragma unroll
            for (int i = 0; i < 4; ++i)
                #pragma unroll
                for (int j = 0; j < 4; ++j)
                    acc[i][j] = __builtin_amdgcn_mfma_f32_16x16x32_f16(af[i], bfm[j], acc[i][j], 0, 0, 0);
        }
        __syncthreads();
    }

    // epilogue: C/D mapping (16x16x32): col = lane&15, row = quad*4 + r
    #pragma unroll
    for (int j = 0; j < 4; ++j) {
        const int col = n0 + wn + j*16 + r16;
        const float bv = (col < 1024) ? c0[col] : (col < 2048) ? c1[col-1024] : c2[col-2048];
        #pragma unroll
        for (int i = 0; i < 4; ++i) {
            #pragma unroll
            for (int r = 0; r < 4; ++r) {
                const int rowg = m0 + wm + i*16 + quad*4 + r;
                out[(size_t)rowg*N + col] = (OT)(acc[i][j][r] + bv);
            }
        }
    }
}

// ---------------------------------------------------------------------------
// Stockham radix-4 DIF FFT, 1024 points, 256 threads, interleaved f32x2 in LDS
// with PAD() physical indexing. No bit-reversal; 5 stages, 1 barrier/stage.
// ---------------------------------------------------------------------------
__device__ inline void fft1024r4(f32x2* x, f32x2* y, const int tid)
{
    f32x2* src = x;
    f32x2* dst = y;
    #pragma unroll
    for (int st = 0; st < 5; ++st) {
        const int ls = 2*st;
        const int s  = 1 << ls;
        const int p  = tid >> ls;
        const int q  = tid & (s - 1);
        const float invn = 1.f / (float)(1024 >> ls);
        const f32x2 a = src[PAD(tid)];
        const f32x2 b = src[PAD(tid + 256)];
        const f32x2 c = src[PAD(tid + 512)];
        const f32x2 d = src[PAD(tid + 768)];
        float ws, wc;
        __sincosf(-2.f*PI_F * (float)p * invn, &ws, &wc);
        const float apcx = a.x + c.x, apcy = a.y + c.y;
        const float amcx = a.x - c.x, amcy = a.y - c.y;
        const float bpdx = b.x + d.x, bpdy = b.y + d.y;
        const float bmdx = b.x - d.x, bmdy = b.y - d.y;
        f32x2 y0; y0.x = apcx + bpdx; y0.y = apcy + bpdy;
        const float t1x = amcx + bmdy, t1y = amcy - bmdx;   // amc - i*bmd
        const float t2x = apcx - bpdx, t2y = apcy - bpdy;
        const float t3x = amcx - bmdy, t3y = amcy + bmdx;   // amc + i*bmd
        const float w2x = wc*wc - ws*ws, w2y = 2.f*wc*ws;
        const float w3x = w2x*wc - w2y*ws, w3y = w2x*ws + w2y*wc;
        f32x2 y1; y1.x = wc*t1x - ws*t1y;   y1.y = wc*t1y + ws*t1x;
        f32x2 y2; y2.x = w2x*t2x - w2y*t2y; y2.y = w2x*t2y + w2y*t2x;
        f32x2 y3; y3.x = w3x*t3x - w3y*t3y; y3.y = w3x*t3y + w3y*t3x;
        const int base = q + ((p * s) << 2);
        dst[PAD(base)]       = y0;
        dst[PAD(base + s)]   = y1;
        dst[PAD(base + 2*s)] = y2;
        dst[PAD(base + 3*s)] = y3;
        __syncthreads();
        f32x2* t = src; src = dst; dst = t;
    }
}

// ---------------------------------------------------------------------------
// FFT-domain attention, two rows per block, packed-real FFTs (f16 in, f16 out):
//   wv = ifft( fft(k) * conj(fft(q)) / 32 * fft(v) ).real
// ---------------------------------------------------------------------------
__global__ __launch_bounds__(256) void fft_attn2(
    const f16* __restrict__ qkv, f16* __restrict__ outg)
{
    __shared__ f32x2 X[PAD(1023)+1], Y[PAD(1023)+1];
    const int tid = threadIdx.x;
    const size_t row0 = (size_t)blockIdx.x * 2;
    const f16* r1 = qkv + row0*QKVN;        // q1 | k1 | v1
    const f16* r2 = r1 + QKVN;              // q2 | k2 | v2

    f32x2 V1[4], V2[4], S1[4], S2[4];

    // ---- FFT(v1 + i*v2) -> V1, V2 in registers ----
    #pragma unroll
    for (int k = 0; k < 4; ++k) {
        const int i = tid + 256*k;
        f32x2 t; t.x = (float)r1[2048+i]; t.y = (float)r2[2048+i];
        X[PAD(i)] = t;
    }
    __syncthreads();
    fft1024r4(X, Y, tid);
    #pragma unroll
    for (int k = 0; k < 4; ++k) {
        const int f = tid + 256*k;
        const int g = (PD - f) & (PD-1);
        const f32x2 z1 = Y[PAD(f)], z2 = Y[PAD(g)];
        V1[k].x = 0.5f*(z1.x + z2.x); V1[k].y = 0.5f*(z1.y - z2.y);
        V2[k].x = 0.5f*(z1.y + z2.y); V2[k].y = 0.5f*(z2.x - z1.x);
    }

    // ---- FFT(q1 + i*k1) ; S1 = conj(K1*conj(Q1)*V1/32) ----
    #pragma unroll
    for (int k = 0; k < 4; ++k) {
        const int i = tid + 256*k;
        f32x2 t; t.x = (float)r1[i]; t.y = (float)r1[1024+i];
        X[PAD(i)] = t;
    }
    __syncthreads();   // fences the V-split reads of Y above
    fft1024r4(X, Y, tid);
    #pragma unroll
    for (int k = 0; k < 4; ++k) {
        const int f = tid + 256*k;
        const int g = (PD - f) & (PD-1);
        const f32x2 z1 = Y[PAD(f)], z2 = Y[PAD(g)];
        const float Qr = 0.5f*(z1.x + z2.x), Qi = 0.5f*(z1.y - z2.y);
        const float Kr = 0.5f*(z1.y + z2.y), Ki = 0.5f*(z2.x - z1.x);
        const float Pr = (Kr*Qr + Ki*Qi) * (1.f/32.f);
        const float Pi = (Ki*Qr - Kr*Qi) * (1.f/32.f);
        S1[k].x = Pr*V1[k].x - Pi*V1[k].y;
        S1[k].y = -(Pr*V1[k].y + Pi*V1[k].x);
    }

    // ---- FFT(q2 + i*k2) ; S2 = conj(K2*conj(Q2)*V2/32) ----
    #pragma unroll
    for (int k = 0; k < 4; ++k) {
        const int i = tid + 256*k;
        f32x2 t; t.x = (float)r2[i]; t.y = (float)r2[1024+i];
        X[PAD(i)] = t;
    }
    __syncthreads();
    fft1024r4(X, Y, tid);
    #pragma unroll
    for (int k = 0; k < 4; ++k) {
        const int f = tid + 256*k;
        const int g = (PD - f) & (PD-1);
        const f32x2 z1 = Y[PAD(f)], z2 = Y[PAD(g)];
        const float Qr = 0.5f*(z1.x + z2.x), Qi = 0.5f*(z1.y - z2.y);
        const float Kr = 0.5f*(z1.y + z2.y), Ki = 0.5f*(z2.x - z1.x);
        const float Pr = (Kr*Qr + Ki*Qi) * (1.f/32.f);
        const float Pi = (Ki*Qr - Kr*Qi) * (1.f/32.f);
        S2[k].x = Pr*V2[k].x - Pi*V2[k].y;
        S2[k].y = -(Pr*V2[k].y + Pi*V2[k].x);
    }

    // ---- packed inverse: FFT(S1 + i*S2) ----
    #pragma unroll
    for (int k = 0; k < 4; ++k) {
        const int f = tid + 256*k;
        f32x2 t; t.x = S1[k].x - S2[k].y; t.y = S1[k].y + S2[k].x;
        X[PAD(f)] = t;
    }
    __syncthreads();
    fft1024r4(X, Y, tid);
    f16* o1 = outg + row0*PD;
    f16* o2 = o1 + PD;
    #pragma unroll
    for (int k = 0; k < 4; ++k) {
        const int n = tid + 256*k;
        const f32x2 z = Y[PAD(n)];
        o1[n] = (f16)(z.x * (1.f/1024.f));
        o2[n] = (f16)(z.y * (1.f/1024.f));
    }
}

// ---------------------------------------------------------------------------
extern "C" void kernel_launch(void* const* d_in, const int* in_sizes, int n_in,
                              void* d_out, int out_size, void* d_ws, size_t ws_size,
                              hipStream_t stream)
{
    const float* x      = (const float*)d_in[0];
    const float* conv_w = (const float*)d_in[1];   // [L,E,1,K]
    const float* conv_b = (const float*)d_in[2];   // [L,E]
    const float* wq     = (const float*)d_in[3];   // [L,P,W]
    const float* bq     = (const float*)d_in[4];   // [L,P]
    const float* wk     = (const float*)d_in[5];
    const float* bk     = (const float*)d_in[6];
    const float* wv     = (const float*)d_in[7];
    const float* bv     = (const float*)d_in[8];
    const float* wo     = (const float*)d_in[9];   // [L,W,P]
    const float* bo     = (const float*)d_in[10];  // [L,W]

    // workspace layout (64 MiB), per-layer weight slots reused:
    //   0M..12M : wqkv16 f16 [3072, 2048]  (q rows 0-1023, k 1024-2047, v 2048-3071)
    //  12M..16M : wo16   f16 [2048, 1024]
    //  16M..40M : qkvbuf f16 [4096, 3072]  (row-interleaved q|k|v)
    //  40M..56M : xc16   f16 [4096, 2048]  (first 8 MiB also aliased wvr16 [4096,1024])
    //  56M..72M : xmid   f16 [4096, 2048]
    char* ws = (char*)d_ws;
    const size_t MB = 1024*1024;
    f16*   wqkv16 = (f16*)(ws);
    f16*   wo16   = (f16*)(ws + 12*MB);
    f16*   qkvbuf = (f16*)(ws + 16*MB);
    f16*   xc16   = (f16*)(ws + 40*MB);
    f16*   xmid   = (f16*)(ws + 56*MB);
    f16*   wvr16  = xc16;   // alias: xc dead once the QKV GEMM completes

    for (int l = 0; l < LN; ++l) {
        // convert this layer's 4 weight tensors in one dispatch
        cvt_layer<<<dim3(4*NWL/4/256), dim3(256), 0, stream>>>(
            wq + (size_t)l*NWL, wk + (size_t)l*NWL, wv + (size_t)l*NWL, wo + (size_t)l*NWL,
            wqkv16, wo16);

        if (l == 0)
            conv_moe<float><<<dim3(MROWS), dim3(256), 0, stream>>>(
                x, conv_w, conv_b, xc16);
        else
            conv_moe<f16><<<dim3(MROWS), dim3(256), 0, stream>>>(
                xmid, conv_w + (size_t)l*ED*KSZ, conv_b + (size_t)l*ED, xc16);

        // qkv = xc @ wqkv^T + [bq|bk|bv]   (M=4096, K=2048, N=3072), f16 out
        gemm_f16<f16><<<dim3(MROWS/128, QKVN/128), dim3(256), 0, stream>>>(
            xc16, wqkv16,
            bq + (size_t)l*PD, bk + (size_t)l*PD, bv + (size_t)l*PD,
            qkvbuf, WD, QKVN);

        fft_attn2<<<dim3(MROWS/2), dim3(256), 0, stream>>>(qkvbuf, wvr16);

        // xnext = wvr @ wo^T + bo  (M=4096, K=1024, N=2048)
        if (l == LN-1)
            gemm_f16<float><<<dim3(MROWS/128, WD/128), dim3(256), 0, stream>>>(
                wvr16, wo16,
                bo + (size_t)l*WD, bo + (size_t)l*WD + PD, bo + (size_t)l*WD + PD,
                (float*)d_out, PD, WD);
        else
            gemm_f16<f16><<<dim3(MROWS/128, WD/128), dim3(256), 0, stream>>>(
                wvr16, wo16,
                bo + (size_t)l*WD, bo + (size_t)l*WD + PD, bo + (size_t)l*WD + PD,
                xmid, PD, WD);
    }
}